// Round 4
// baseline (39.487 us; speedup 1.0000x reference)
//
#include <hip/hip_runtime.h>
#include <stdint.h>

// WeightedMSELoss: mean((p-t)^2 * w), w=3.0 at per-row top-5 of t.
// Hierarchical top-k: row top-5 subset-of union of per-chunk top-5.
// Stage 1: one wave per 512-elem chunk, barrier-free, writes 5 packed
//          (key<<32|loss) candidates + partial ssq.
// Stage 2: one thread per row merges 8 chunks' candidates -> row sum -> partials.
// Stage 3: one wave reduces 64 partials -> mean.
// B=N=4096 fp32 in, fp32 scalar out.

typedef unsigned long long u64;

static constexpr int NROW = 4096;
static constexpr int NCOL = 4096;
static constexpr int CHUNK = 512;                  // elems per wave
static constexpr int CPR = NCOL / CHUNK;           // 8 chunks per row
static constexpr int NCHUNK = NROW * CPR;          // 32768
static constexpr int WPB = 4;                      // independent waves per block
static constexpr int BDIM = WPB * 64;

__device__ __forceinline__ uint32_t f32_mono(float f) {
    // order-preserving f32 -> u32 (no NaNs in input)
    uint32_t u = __float_as_uint(f);
    return u ^ (uint32_t)(((int32_t)u >> 31) | (int32_t)0x80000000);
}

__global__ __launch_bounds__(BDIM) void wmse_chunks(const float* __restrict__ preds,
                                                    const float* __restrict__ tgts,
                                                    u64* __restrict__ top5,
                                                    float* __restrict__ ssqs) {
    const int chunk = blockIdx.x * WPB + (threadIdx.x >> 6);
    const int lane = threadIdx.x & 63;

    const float4* p4 = reinterpret_cast<const float4*>(preds) + (size_t)chunk * (CHUNK / 4) + lane;
    const float4* t4 = reinterpret_cast<const float4*>(tgts) + (size_t)chunk * (CHUNK / 4) + lane;

    // all 4 loads issued before any use
    const float4 pa = p4[0];
    const float4 pb = p4[64];
    const float4 ta = t4[0];
    const float4 tb = t4[64];

    float ls[8];
    u64 pk[8];
    {
        const float d0 = pa.x - ta.x, d1 = pa.y - ta.y, d2 = pa.z - ta.z, d3 = pa.w - ta.w;
        const float e0 = pb.x - tb.x, e1 = pb.y - tb.y, e2 = pb.z - tb.z, e3 = pb.w - tb.w;
        ls[0] = d0 * d0; ls[1] = d1 * d1; ls[2] = d2 * d2; ls[3] = d3 * d3;
        ls[4] = e0 * e0; ls[5] = e1 * e1; ls[6] = e2 * e2; ls[7] = e3 * e3;
        pk[0] = ((u64)f32_mono(ta.x) << 32) | __float_as_uint(ls[0]);
        pk[1] = ((u64)f32_mono(ta.y) << 32) | __float_as_uint(ls[1]);
        pk[2] = ((u64)f32_mono(ta.z) << 32) | __float_as_uint(ls[2]);
        pk[3] = ((u64)f32_mono(ta.w) << 32) | __float_as_uint(ls[3]);
        pk[4] = ((u64)f32_mono(tb.x) << 32) | __float_as_uint(ls[4]);
        pk[5] = ((u64)f32_mono(tb.y) << 32) | __float_as_uint(ls[5]);
        pk[6] = ((u64)f32_mono(tb.z) << 32) | __float_as_uint(ls[6]);
        pk[7] = ((u64)f32_mono(tb.w) << 32) | __float_as_uint(ls[7]);
    }

    float ssq = ((ls[0] + ls[1]) + (ls[2] + ls[3])) + ((ls[4] + ls[5]) + (ls[6] + ls[7]));
#pragma unroll
    for (int sh = 32; sh >= 1; sh >>= 1) {
        ssq += __shfl_xor(ssq, sh, 64);
    }

    // 5 rounds: wave-max of packed keys strictly below previous winner
    u64 prev = ~0ull;
    u64 mine = 0;
#pragma unroll
    for (int r = 0; r < 5; ++r) {
        u64 c = 0;
#pragma unroll
        for (int i = 0; i < 8; ++i) {
            c = (pk[i] < prev && pk[i] > c) ? pk[i] : c;
        }
#pragma unroll
        for (int sh = 32; sh >= 1; sh >>= 1) {
            const u64 o = __shfl_xor(c, sh, 64);
            c = (o > c) ? o : c;
        }
        if (lane == r) mine = c;
        prev = c;
    }

    if (lane < 5) top5[(size_t)chunk * 5 + lane] = mine;
    if (lane == 0) ssqs[chunk] = ssq;
}

__global__ __launch_bounds__(64) void wmse_merge(const u64* __restrict__ top5,
                                                 const float* __restrict__ ssqs,
                                                 double* __restrict__ partials) {
    const int row = blockIdx.x * 64 + threadIdx.x;
    const u64* t = top5 + (size_t)row * (5 * CPR);

    // streaming 5-slot insert over the row's 40 candidates
    u64 s0 = 0, s1 = 0, s2 = 0, s3 = 0, s4 = 0;
#pragma unroll
    for (int j = 0; j < 5 * CPR; ++j) {
        u64 v = t[j], m;
        m = s0 > v ? s0 : v; v = s0 > v ? v : s0; s0 = m;
        m = s1 > v ? s1 : v; v = s1 > v ? v : s1; s1 = m;
        m = s2 > v ? s2 : v; v = s2 > v ? v : s2; s2 = m;
        m = s3 > v ? s3 : v; v = s3 > v ? v : s3; s3 = m;
        m = s4 > v ? s4 : v; v = s4 > v ? v : s4; s4 = m;
    }
    const float extra = __uint_as_float((uint32_t)s0) + __uint_as_float((uint32_t)s1) +
                        __uint_as_float((uint32_t)s2) + __uint_as_float((uint32_t)s3) +
                        __uint_as_float((uint32_t)s4);
    float ss = 0.f;
#pragma unroll
    for (int q = 0; q < CPR; ++q) {
        ss += ssqs[row * CPR + q];
    }

    double rsum = (double)ss + 2.0 * (double)extra; // weight 3 = 1 + 2
#pragma unroll
    for (int sh = 32; sh >= 1; sh >>= 1) {
        rsum += __shfl_xor(rsum, sh, 64);
    }
    if (threadIdx.x == 0) partials[blockIdx.x] = rsum;
}

__global__ __launch_bounds__(64) void wmse_final(const double* __restrict__ partials,
                                                 float* __restrict__ out) {
    double v = partials[threadIdx.x];
#pragma unroll
    for (int sh = 32; sh >= 1; sh >>= 1) {
        v += __shfl_xor(v, sh, 64);
    }
    if (threadIdx.x == 0) {
        out[0] = (float)(v / ((double)NROW * (double)NCOL));
    }
}

extern "C" void kernel_launch(void* const* d_in, const int* in_sizes, int n_in,
                              void* d_out, int out_size, void* d_ws, size_t ws_size,
                              hipStream_t stream) {
    const float* preds = (const float*)d_in[0];
    const float* tgts = (const float*)d_in[1];

    // ws layout (1.41 MB total):
    u64* top5 = (u64*)d_ws;                                   // 32768*5*8 = 1310720 B
    float* ssqs = (float*)((char*)d_ws + 1310720);            // 131072 B
    double* partials = (double*)((char*)d_ws + 1441792);      // 512 B
    float* out = (float*)d_out;

    wmse_chunks<<<NCHUNK / WPB, BDIM, 0, stream>>>(preds, tgts, top5, ssqs);
    wmse_merge<<<NROW / 64, 64, 0, stream>>>(top5, ssqs, partials);
    wmse_final<<<1, 64, 0, stream>>>(partials, out);
}